// Round 2
// baseline (4471.355 us; speedup 1.0000x reference)
//
#include <hip/hip_runtime.h>

// ---------------------------------------------------------------------------
// VolumeAttention: 4 feature levels x 6 decoder depths, B=4, NQ=100, C=256, H=8
// Round 2:
//  - flash split-K attention re-chunked 512->128 keys/block (occupancy 13%->~60%)
//    + Kt bank-swizzle (col ^= row&16)
//  - KV projection (M=21760,N=512,K=256) moved to MFMA 16x16x32 bf16 with
//    split-precision (hi+lo bf16, 3 MFMAs) -- error ~2^-17 relative
//  - W^T pre-split/pre-transposed per call; LN still fused into A staging
// ---------------------------------------------------------------------------

#define DI __device__ __forceinline__

typedef __attribute__((ext_vector_type(8))) short bf16x8;
typedef __attribute__((ext_vector_type(4))) float f32x4;

// ws offsets in floats
constexpr long O_KV    = 0;                        // [21760][512] per-view K|V
constexpr long O_QBUF  = O_KV    + 21760L * 512;   // [1600][256] current q
constexpr long O_QKV   = O_QBUF  + 409600;         // [1600][768] self-attn qkv
constexpr long O_QSA   = O_QKV   + 1228800;        // [1600][256]
constexpr long O_QHAT  = O_QSA   + 409600;         // [1600][256]
constexpr long O_QN    = O_QHAT  + 409600;         // [1600][256]
constexpr long O_SAO   = O_QN    + 409600;         // [1600][256]
constexpr long O_OCA   = O_SAO   + 409600;         // [2][1600][256]
constexpr long O_Q12   = O_OCA   + 819200;         // [2][1600][256]
constexpr long O_WTH   = O_Q12   + 819200;         // [6][512][256] ushort hi (as 393216 floats)
constexpr long O_WTL   = O_WTH   + 393216;         // [6][512][256] ushort lo
constexpr long O_WQ    = O_WTL   + 393216;         // [6][256][256] folded Wq fp32
constexpr long O_BKV   = O_WQ    + 393216;         // [6][512]
constexpr long O_BQ    = O_BKV   + 3072;           // [6][256]
constexpr long O_PO    = O_BQ    + 1536;           // [1376][3200] flash partial O
constexpr long O_PM    = O_PO    + 1376L * 3200;   // [1376][128]
constexpr long O_PL    = O_PM    + 176128;         // [1376][128]
constexpr long O_MS    = O_PL    + 176128;         // [16][128][128]
constexpr long O_RST   = O_MS    + 262144;         // [4][16][128]
constexpr long O_STATS = O_RST   + 8192;           // [43520][2] token mean/rstd
constexpr long WS_FLOATS = O_STATS + 87040;        // ~89.4 MB

DI int sel4(int4 v, int i) { return i == 0 ? v.x : (i == 1 ? v.y : (i == 2 ? v.z : v.w)); }
DI float dot4(float4 a, float4 b) {
  float s = a.x * b.x;
  s = fmaf(a.y, b.y, s); s = fmaf(a.z, b.z, s); s = fmaf(a.w, b.w, s);
  return s;
}
DI unsigned short bf_rne(float x) {
  unsigned u = __float_as_uint(x);
  u += 0x7fffu + ((u >> 16) & 1u);
  return (unsigned short)(u >> 16);
}
DI float bf2f(unsigned short h) { return __uint_as_float(((unsigned)h) << 16); }

// --- fold LN affine into projections; KV weights -> transposed split-bf16 --
// WTh/WTl layout: [d][n(512)][k(256)] ushort (k fastest -> b128 frag reads)
__global__ void fold_w2_kernel(const float* __restrict__ ng, const float* __restrict__ wk,
                               const float* __restrict__ wv, const float* __restrict__ wq,
                               unsigned short* __restrict__ WTh, unsigned short* __restrict__ WTl,
                               float* __restrict__ wqo) {
  long idx = (long)blockIdx.x * 256 + threadIdx.x;
  const long T1 = 6L * 512 * 256;
  if (idx < T1) {
    int d = idx / (512 * 256); int r = idx % (512 * 256); int n = r / 256; int k = r % 256;
    float g = ng[d * 256 + k];
    float w = (n < 256) ? wk[((long)(d * 256 + k)) * 256 + n]
                        : wv[((long)(d * 256 + k)) * 256 + (n - 256)];
    w *= g;
    unsigned short h = bf_rne(w);
    WTh[idx] = h;
    WTl[idx] = bf_rne(w - bf2f(h));
  } else {
    long j = idx - T1;
    if (j < 6L * 256 * 256) {
      int d = j / 65536; int r = j % 65536; int c = r / 256; int n = r % 256;
      wqo[j] = ng[d * 256 + c] * wq[((long)(d * 256 + c)) * 256 + n];
    }
  }
}

__global__ void fold_b_kernel(const float* __restrict__ nb, const float* __restrict__ wk,
                              const float* __restrict__ wv, const float* __restrict__ wq,
                              float* __restrict__ bkvo, float* __restrict__ bqo) {
  int idx = blockIdx.x * 256 + threadIdx.x;
  if (idx >= 6 * 768) return;
  int d = idx / 768, j = idx % 768;
  float s = 0.f;
  if (j < 256) {
    for (int c = 0; c < 256; ++c) s = fmaf(nb[d * 256 + c], wk[(d * 256 + c) * 256 + j], s);
    bkvo[d * 512 + j] = s;
  } else if (j < 512) {
    int n = j - 256;
    for (int c = 0; c < 256; ++c) s = fmaf(nb[d * 256 + c], wv[(d * 256 + c) * 256 + n], s);
    bkvo[d * 512 + j] = s;
  } else {
    int n = j - 512;
    for (int c = 0; c < 256; ++c) s = fmaf(nb[d * 256 + c], wq[(d * 256 + c) * 256 + n], s);
    bqo[d * 256 + n] = s;
  }
}

// --- per-token LN statistics of feature maps ------------------------------
__global__ __launch_bounds__(256) void ln_stats_kernel(const float* __restrict__ feat,
                                                       float* __restrict__ stats,
                                                       int rowBase, int HW) {
  __shared__ float sred[4][64];
  __shared__ float qred[4][64];
  int b = blockIdx.y, t0 = blockIdx.x * 64;
  int tx = threadIdx.x & 63, ty = threadIdx.x >> 6;
  const float* fb = feat + (long)b * 256 * HW;
  float s = 0.f, q = 0.f;
  for (int k = 0; k < 64; ++k) {
    int c = ty * 64 + k;
    float v = fb[(long)c * HW + t0 + tx];
    s += v; q += v * v;
  }
  sred[ty][tx] = s; qred[ty][tx] = q;
  __syncthreads();
  if (ty == 0) {
    float ts = sred[0][tx] + sred[1][tx] + sred[2][tx] + sred[3][tx];
    float tq = qred[0][tx] + qred[1][tx] + qred[2][tx] + qred[3][tx];
    float m = ts * (1.f / 256.f);
    float var = tq * (1.f / 256.f) - m * m;
    int row = rowBase + b * HW + t0 + tx;
    stats[row * 2 + 0] = m;
    stats[row * 2 + 1] = rsqrtf(var + 1e-5f);
  }
}

__global__ void init_q_kernel(const float* __restrict__ qe, float* __restrict__ qb) {
  int idx = blockIdx.x * 256 + threadIdx.x;
  if (idx < 1600 * 256) {
    int row = idx >> 8, c = idx & 255;
    qb[idx] = qe[(row % 100) * 256 + c];
  }
}

// --- generic fp32 GEMM: C[M,N] = A[M,256] @ W[256,N] (+bias) --------------
__global__ __launch_bounds__(256) void gemm256_kernel(const float* __restrict__ A,
                                                      const float* __restrict__ W,
                                                      const float* __restrict__ bias,
                                                      float* __restrict__ Co, int M, int N) {
  __shared__ float As[32][68];
  __shared__ float Ws[32][68];
  int tid = threadIdx.x;
  int tm = tid & 15, tn = tid >> 4;
  int m0 = blockIdx.y * 64, n0 = blockIdx.x * 64;
  float acc[4][4] = {};
  for (int kt = 0; kt < 8; ++kt) {
    __syncthreads();
#pragma unroll
    for (int it = 0; it < 2; ++it) {
      int i = tid + it * 256;
      int r = i >> 3, c4 = (i & 7) * 4;
      float4 f = *(const float4*)&A[(long)(m0 + r) * 256 + kt * 32 + c4];
      As[c4 + 0][r] = f.x; As[c4 + 1][r] = f.y; As[c4 + 2][r] = f.z; As[c4 + 3][r] = f.w;
    }
#pragma unroll
    for (int it = 0; it < 2; ++it) {
      int i = tid + it * 256;
      int r = i >> 4, c4 = (i & 15) * 4;
      *(float4*)&Ws[r][c4] = *(const float4*)&W[(long)(kt * 32 + r) * N + n0 + c4];
    }
    __syncthreads();
#pragma unroll
    for (int k = 0; k < 32; ++k) {
      float4 a4 = *(const float4*)&As[k][4 * tm];
      float4 b4 = *(const float4*)&Ws[k][4 * tn];
      float av[4] = {a4.x, a4.y, a4.z, a4.w};
      float bv[4] = {b4.x, b4.y, b4.z, b4.w};
#pragma unroll
      for (int i = 0; i < 4; ++i)
#pragma unroll
        for (int j = 0; j < 4; ++j) acc[i][j] = fmaf(av[i], bv[j], acc[i][j]);
    }
  }
  float bv4[4] = {0.f, 0.f, 0.f, 0.f};
  if (bias) {
#pragma unroll
    for (int j = 0; j < 4; ++j) bv4[j] = bias[n0 + 4 * tn + j];
  }
#pragma unroll
  for (int i = 0; i < 4; ++i) {
    int row = m0 + 4 * tm + i;
    float4 o;
    o.x = acc[i][0] + bv4[0]; o.y = acc[i][1] + bv4[1];
    o.z = acc[i][2] + bv4[2]; o.w = acc[i][3] + bv4[3];
    *(float4*)&Co[(long)row * N + n0 + 4 * tn] = o;
  }
}

// --- KV projection via MFMA, split-bf16 ------------------------------------
// KV[m, n] = LNhat(tok[m]) @ Wkv'[k, n] + bkv'[n];  M=21760, N=512, K=256
// grid (8 n-blocks, 340 m-blocks), 256 thr = 4 waves; wave w owns rows w*16..+16.
__global__ __launch_bounds__(256) void gemm_kv_mfma_kernel(
    const float* __restrict__ f0, const float* __restrict__ f1,
    const float* __restrict__ f2, const float* __restrict__ f3,
    const float* __restrict__ stats, int vbase,
    const unsigned short* __restrict__ Wh, const unsigned short* __restrict__ Wl,
    const float* __restrict__ bias, float* __restrict__ Co) {
  __shared__ unsigned short Ah[64][72], Al[64][72];   // [m][k] bf16, pad 8
  __shared__ unsigned short Bh[64][72], Bl[64][72];   // [n][k] bf16
  __shared__ float sm[64], sr[64];
  int tid = threadIdx.x;
  int m0 = blockIdx.y * 64, n0 = blockIdx.x * 64;
  const float* fp; int HW, rel;
  if (m0 < 16384)      { fp = f0; HW = 4096; rel = m0; }
  else if (m0 < 20480) { fp = f1; HW = 1024; rel = m0 - 16384; }
  else if (m0 < 21504) { fp = f2; HW = 256;  rel = m0 - 20480; }
  else                 { fp = f3; HW = 64;   rel = m0 - 21504; }
  int b = rel / HW, t0 = rel % HW;
  const float* fb = fp + (long)b * 256 * HW + t0;
  if (tid < 64) {
    sm[tid] = stats[(vbase + m0 + tid) * 2 + 0];
    sr[tid] = stats[(vbase + m0 + tid) * 2 + 1];
  }
  int wv = tid >> 6, lane = tid & 63;
  int fr = lane & 15;   // MFMA row/col within 16
  int kq = lane >> 4;   // k-quarter: k0 = 8*kq
  f32x4 acc[4];
#pragma unroll
  for (int c = 0; c < 4; ++c)
#pragma unroll
    for (int r = 0; r < 4; ++r) acc[c][r] = 0.f;
  __syncthreads();  // sm/sr ready
  for (int kc = 0; kc < 4; ++kc) {  // 4 chunks of 64 k
    // --- stage A (64m x 64k): thread -> m=lane, k-group=wv ---
    {
      float mean = sm[lane], rstd = sr[lane];
#pragma unroll
      for (int pass = 0; pass < 4; ++pass) {
        int k = pass * 16 + wv * 4;
        float xs[4];
#pragma unroll
        for (int i = 0; i < 4; ++i)
          xs[i] = (fb[(long)(kc * 64 + k + i) * HW + lane] - mean) * rstd;
        ushort4 uh, ul;
        uh.x = bf_rne(xs[0]); ul.x = bf_rne(xs[0] - bf2f(uh.x));
        uh.y = bf_rne(xs[1]); ul.y = bf_rne(xs[1] - bf2f(uh.y));
        uh.z = bf_rne(xs[2]); ul.z = bf_rne(xs[2] - bf2f(uh.z));
        uh.w = bf_rne(xs[3]); ul.w = bf_rne(xs[3] - bf2f(uh.w));
        *(ushort4*)&Ah[lane][k] = uh;
        *(ushort4*)&Al[lane][k] = ul;
      }
    }
    // --- stage B (64n x 64k): thread -> n=pass*16+(tid>>4), k4=(tid&15)*4 ---
    {
      int ks = (tid & 15) * 4;
#pragma unroll
      for (int pass = 0; pass < 4; ++pass) {
        int n = pass * 16 + (tid >> 4);
        long g = (long)(n0 + n) * 256 + kc * 64 + ks;
        *(ushort4*)&Bh[n][ks] = *(const ushort4*)&Wh[g];
        *(ushort4*)&Bl[n][ks] = *(const ushort4*)&Wl[g];
      }
    }
    __syncthreads();
#pragma unroll
    for (int s = 0; s < 2; ++s) {  // two K=32 steps
      int k0 = s * 32 + kq * 8;
      bf16x8 a_h = *(const bf16x8*)&Ah[wv * 16 + fr][k0];
      bf16x8 a_l = *(const bf16x8*)&Al[wv * 16 + fr][k0];
#pragma unroll
      for (int c = 0; c < 4; ++c) {
        bf16x8 b_h = *(const bf16x8*)&Bh[c * 16 + fr][k0];
        bf16x8 b_l = *(const bf16x8*)&Bl[c * 16 + fr][k0];
        acc[c] = __builtin_amdgcn_mfma_f32_16x16x32_bf16(a_h, b_h, acc[c], 0, 0, 0);
        acc[c] = __builtin_amdgcn_mfma_f32_16x16x32_bf16(a_l, b_h, acc[c], 0, 0, 0);
        acc[c] = __builtin_amdgcn_mfma_f32_16x16x32_bf16(a_h, b_l, acc[c], 0, 0, 0);
      }
    }
    __syncthreads();
  }
  // epilogue: D row = 4*kq + r, col = fr (per 16x16 tile)
  int row0 = m0 + wv * 16 + kq * 4;
#pragma unroll
  for (int c = 0; c < 4; ++c) {
    float bv = bias[n0 + c * 16 + fr];
#pragma unroll
    for (int r = 0; r < 4; ++r)
      Co[(long)(row0 + r) * 512 + n0 + c * 16 + fr] = acc[c][r] + bv;
  }
}

// --- row LayerNorm (no affine) ---------------------------------------------
__global__ __launch_bounds__(256) void row_ln_kernel(const float* __restrict__ in,
                                                     float* __restrict__ out) {
  __shared__ float s1[4], s2[4];
  long r = blockIdx.x;
  float x = in[r * 256 + threadIdx.x];
  float vs = x, vq = x * x;
  for (int o = 32; o; o >>= 1) { vs += __shfl_xor(vs, o); vq += __shfl_xor(vq, o); }
  int w = threadIdx.x >> 6;
  if ((threadIdx.x & 63) == 0) { s1[w] = vs; s2[w] = vq; }
  __syncthreads();
  float ts = s1[0] + s1[1] + s1[2] + s1[3];
  float tq = s2[0] + s2[1] + s2[2] + s2[3];
  float m = ts * (1.f / 256.f);
  float var = tq * (1.f / 256.f) - m * m;
  out[r * 256 + threadIdx.x] = (x - m) * rsqrtf(var + 1e-5f);
}

// --- flash split-K attention (128-key chunks) ------------------------------
__global__ __launch_bounds__(256) void flash_kernel(const float* __restrict__ qp, int qld,
                                                    const float* __restrict__ kb,
                                                    const float* __restrict__ vb, int kvld,
                                                    int4 startv, int4 nchv, int4 nkv,
                                                    int4 koffv, int4 kstrbv,
                                                    float* __restrict__ po,
                                                    float* __restrict__ pm,
                                                    float* __restrict__ pl) {
  __shared__ float Kt[32][36];
  __shared__ float Vt[32][36];
  int bid = blockIdx.x;
  int s1 = startv.y, s2 = startv.z, s3 = startv.w;
  int l = (bid < s1) ? 0 : (bid < s2) ? 1 : (bid < s3) ? 2 : 3;
  int r = bid - sel4(startv, l);
  int nc = sel4(nchv, l);
  int b = r / (8 * nc);
  int h = (r / nc) & 7;
  int ch = r % nc;
  int Nk = sel4(nkv, l);
  int qr0 = (l * 4 + b) * 100;
  int kr0 = sel4(koffv, l) + b * sel4(kstrbv, l);
  int j0 = ch * 128;
  int jn = min(128, Nk - j0);
  int tiles = (jn + 31) >> 5;
  int tid = threadIdx.x;
  int qi = tid >> 1, half = tid & 1, ho = half * 16, jb = half * 16;
  const float SC = 0.17677669529663689f;  // 32^-0.5
  float4 q8[8];
  if (qi < 100) {
    const float* qrow = qp + (long)(qr0 + qi) * qld + h * 32;
#pragma unroll
    for (int k = 0; k < 8; ++k) {
      float4 f = *(const float4*)&qrow[4 * k];
      q8[k] = make_float4(f.x * SC, f.y * SC, f.z * SC, f.w * SC);
    }
  } else {
#pragma unroll
    for (int k = 0; k < 8; ++k) q8[k] = make_float4(0.f, 0.f, 0.f, 0.f);
  }
  float m = -1e30f, lsum = 0.f;
  float o[16];
#pragma unroll
  for (int i = 0; i < 16; ++i) o[i] = 0.f;

  for (int kt = 0; kt < tiles; ++kt) {
    __syncthreads();
    {
      int rr = tid >> 3, c4 = (tid & 7) * 4;
      int jr = kt * 32 + rr;
      float4 kf = make_float4(0.f, 0.f, 0.f, 0.f), vf = kf;
      if (jr < jn) {
        long g = (long)(kr0 + j0 + jr) * kvld + h * 32 + c4;
        kf = *(const float4*)&kb[g];
        vf = *(const float4*)&vb[g];
      }
      *(float4*)&Kt[rr][c4 ^ (rr & 16)] = kf;   // bank swizzle on K only
      *(float4*)&Vt[rr][c4] = vf;
    }
    __syncthreads();
    float sv[16];
#pragma unroll
    for (int j = 0; j < 16; ++j) {
      float s = 0.f;
#pragma unroll
      for (int k4 = 0; k4 < 8; ++k4) {
        float4 kv = *(const float4*)&Kt[jb + j][(4 * k4) ^ jb];
        s = fmaf(q8[k4].x, kv.x, s); s = fmaf(q8[k4].y, kv.y, s);
        s = fmaf(q8[k4].z, kv.z, s); s = fmaf(q8[k4].w, kv.w, s);
      }
      int jglob = j0 + kt * 32 + jb + j;
      sv[j] = (jglob < Nk) ? s : -1e30f;
    }
    float tmax = sv[0];
#pragma unroll
    for (int j = 1; j < 16; ++j) tmax = fmaxf(tmax, sv[j]);
    tmax = fmaxf(tmax, __shfl_xor(tmax, 1));
    float mnew = fmaxf(m, tmax);
    float scale = __expf(m - mnew);
    float p[16]; float psum = 0.f;
#pragma unroll
    for (int j = 0; j < 16; ++j) {
      int jglob = j0 + kt * 32 + jb + j;
      float e = (jglob < Nk) ? __expf(sv[j] - mnew) : 0.f;
      p[j] = e; psum += e;
    }
    psum += __shfl_xor(psum, 1);
    lsum = lsum * scale + psum;
    m = mnew;
#pragma unroll
    for (int i = 0; i < 16; ++i) o[i] *= scale;
    float pO[16];
#pragma unroll
    for (int j = 0; j < 16; ++j) pO[j] = __shfl_xor(p[j], 1);
    int jbO = jb ^ 16;
#pragma unroll
    for (int j = 0; j < 16; ++j) {
      float pj = p[j];
      const float* vrow = &Vt[jb + j][ho];
#pragma unroll
      for (int k = 0; k < 4; ++k) {
        float4 v4 = *(const float4*)&vrow[4 * k];
        o[4 * k + 0] = fmaf(pj, v4.x, o[4 * k + 0]);
        o[4 * k + 1] = fmaf(pj, v4.y, o[4 * k + 1]);
        o[4 * k + 2] = fmaf(pj, v4.z, o[4 * k + 2]);
        o[4 * k + 3] = fmaf(pj, v4.w, o[4 * k + 3]);
      }
    }
#pragma unroll
    for (int j = 0; j < 16; ++j) {
      float pj = pO[j];
      const float* vrow = &Vt[jbO + j][ho];
#pragma unroll
      for (int k = 0; k < 4; ++k) {
        float4 v4 = *(const float4*)&vrow[4 * k];
        o[4 * k + 0] = fmaf(pj, v4.x, o[4 * k + 0]);
        o[4 * k + 1] = fmaf(pj, v4.y, o[4 * k + 1]);
        o[4 * k + 2] = fmaf(pj, v4.z, o[4 * k + 2]);
        o[4 * k + 3] = fmaf(pj, v4.w, o[4 * k + 3]);
      }
    }
  }
  if (qi < 100) {
    float* pod = po + (long)bid * 3200 + qi * 32 + ho;
#pragma unroll
    for (int k = 0; k < 4; ++k)
      *(float4*)&pod[4 * k] = make_float4(o[4 * k], o[4 * k + 1], o[4 * k + 2], o[4 * k + 3]);
    if (half == 0) { pm[bid * 128 + qi] = m; pl[bid * 128 + qi] = lsum; }
  }
}

// --- combine flash partials -------------------------------------------------
__global__ __launch_bounds__(256) void combine_kernel(const float* __restrict__ po,
                                                      const float* __restrict__ pm,
                                                      const float* __restrict__ pl,
                                                      int4 startv, int4 nchv,
                                                      float* __restrict__ outp, int outld) {
  int bid = blockIdx.x;
  int l = bid >> 5, rr = bid & 31, b = rr >> 3, h = rr & 7;
  int nc = sel4(nchv, l);
  int sb = sel4(startv, l) + (b * 8 + h) * nc;
  int qr0 = (l * 4 + b) * 100;
  for (int idx = threadIdx.x; idx < 3200; idx += 256) {
    int qi = idx >> 5, hd = idx & 31;
    float mstar = -1e30f;
    for (int c = 0; c < nc; ++c) mstar = fmaxf(mstar, pm[(sb + c) * 128 + qi]);
    float Lt = 0.f, val = 0.f;
    for (int c = 0; c < nc; ++c) {
      float w = __expf(pm[(sb + c) * 128 + qi] - mstar);
      Lt = fmaf(w, pl[(sb + c) * 128 + qi], Lt);
      val = fmaf(w, po[(long)(sb + c) * 3200 + qi * 32 + hd], val);
    }
    outp[(long)(qr0 + qi) * outld + h * 32 + hd] = val / Lt;
  }
}

// --- ms = q1 @ q2^T ---------------------------------------------------------
__global__ __launch_bounds__(256) void fuse_ms_kernel(const float* __restrict__ q1,
                                                      const float* __restrict__ q2,
                                                      float* __restrict__ ms) {
  __shared__ float a[32][132];
  __shared__ float bsh[32][132];
  int lb = blockIdx.x;
  int it = blockIdx.y >> 2, jt = blockIdx.y & 3;
  int tid = threadIdx.x;
  int ti = tid & 15, tj = tid >> 4;
  float acc[2][2] = {};
  for (int chalf = 0; chalf < 2; ++chalf) {
    __syncthreads();
#pragma unroll
    for (int k = 0; k < 4; ++k) {
      int i = tid + k * 256;
      int rr = i >> 5, c4 = (i & 31) * 4;
      int row1 = it * 32 + rr, row2 = jt * 32 + rr;
      float4 fa = make_float4(0.f, 0.f, 0.f, 0.f), fb = fa;
      if (row1 < 100) fa = *(const float4*)&q1[(long)(lb * 100 + row1) * 256 + chalf * 128 + c4];
      if (row2 < 100) fb = *(const float4*)&q2[(long)(lb * 100 + row2) * 256 + chalf * 128 + c4];
      *(float4*)&a[rr][c4] = fa;
      *(float4*)&bsh[rr][c4] = fb;
    }
    __syncthreads();
#pragma unroll
    for (int k4 = 0; k4 < 32; ++k4) {
      float4 a0 = *(const float4*)&a[2 * ti][4 * k4];
      float4 a1 = *(const float4*)&a[2 * ti + 1][4 * k4];
      float4 b0 = *(const float4*)&bsh[2 * tj][4 * k4];
      float4 b1 = *(const float4*)&bsh[2 * tj + 1][4 * k4];
      acc[0][0] += dot4(a0, b0); acc[0][1] += dot4(a0, b1);
      acc[1][0] += dot4(a1, b0); acc[1][1] += dot4(a1, b1);
    }
  }
#pragma unroll
  for (int i = 0; i < 2; ++i)
#pragma unroll
    for (int j = 0; j < 2; ++j)
      ms[(long)(lb * 128 + it * 32 + 2 * ti + i) * 128 + jt * 32 + 2 * tj + j] = acc[i][j];
}

// --- row & column softmax stats of ms --------------------------------------
__global__ void fuse_stats_kernel(const float* __restrict__ ms, float* __restrict__ rst) {
  int lb = blockIdx.x, tid = threadIdx.x;
  if (tid < 100) {
    const float* row = ms + (long)(lb * 128 + tid) * 128;
    float mx = row[0];
    for (int j = 1; j < 100; ++j) mx = fmaxf(mx, row[j]);
    float s = 0.f;
    for (int j = 0; j < 100; ++j) s += __expf(row[j] - mx);
    rst[(0 * 16 + lb) * 128 + tid] = mx;
    rst[(1 * 16 + lb) * 128 + tid] = s;
  } else if (tid >= 128 && tid < 228) {
    int j = tid - 128;
    const float* colp = ms + (long)lb * 128 * 128 + j;
    float mx = colp[0];
    for (int i = 1; i < 100; ++i) mx = fmaxf(mx, colp[i * 128]);
    float s = 0.f;
    for (int i = 0; i < 100; ++i) s += __expf(colp[i * 128] - mx);
    rst[(2 * 16 + lb) * 128 + j] = mx;
    rst[(3 * 16 + lb) * 128 + j] = s;
  }
}

// --- r1/r2 mixing + final channel softmax -----------------------------------
__global__ __launch_bounds__(256) void fuse_apply_kernel(const float* __restrict__ ms,
                                                         const float* __restrict__ rst,
                                                         const float* __restrict__ q1,
                                                         const float* __restrict__ q2,
                                                         const float* __restrict__ qsa,
                                                         float* __restrict__ qout) {
  __shared__ float pr[100], pc[100];
  __shared__ float red1[4], red2[4];
  int lb = blockIdx.x, qc = blockIdx.y, tid = threadIdx.x;
  for (int ii = 0; ii < 10; ++ii) {
    int i = qc * 10 + ii;
    long r = lb * 100 + i;
    if (tid < 100) {
      float rm = rst[(0 * 16 + lb) * 128 + i], rs = rst[(1 * 16 + lb) * 128 + i];
      pr[tid] = __expf(ms[(long)(lb * 128 + i) * 128 + tid] - rm) / rs;
    } else if (tid >= 128 && tid < 228) {
      int i2 = tid - 128;
      float cm = rst[(2 * 16 + lb) * 128 + i], cs = rst[(3 * 16 + lb) * 128 + i];
      pc[i2] = __expf(ms[(long)(lb * 128 + i2) * 128 + i] - cm) / cs;
    }
    __syncthreads();
    float acc1 = 0.f, acc2 = 0.f;
    for (int j = 0; j < 100; ++j) acc1 = fmaf(pr[j], q2[(long)(lb * 100 + j) * 256 + tid], acc1);
    for (int j = 0; j < 100; ++j) acc2 = fmaf(pc[j], q1[(long)(lb * 100 + j) * 256 + tid], acc2);
    float z = qsa[r * 256 + tid] + q1[r * 256 + tid] + acc1 + q2[r * 256 + tid] + acc2;
    float v = z;
    for (int off = 32; off; off >>= 1) v = fmaxf(v, __shfl_xor(v, off));
    int w = tid >> 6;
    if ((tid & 63) == 0) red1[w] = v;
    __syncthreads();
    float zm = fmaxf(fmaxf(red1[0], red1[1]), fmaxf(red1[2], red1[3]));
    float e = __expf(z - zm);
    float sv = e;
    for (int off = 32; off; off >>= 1) sv += __shfl_xor(sv, off);
    if ((tid & 63) == 0) red2[w] = sv;
    __syncthreads();
    float es = red2[0] + red2[1] + red2[2] + red2[3];
    qout[r * 256 + tid] = e / es;
    __syncthreads();
  }
}

// ---------------------------------------------------------------------------
extern "C" void kernel_launch(void* const* d_in, const int* in_sizes, int n_in,
                              void* d_out, int out_size, void* d_ws, size_t ws_size,
                              hipStream_t stream) {
  (void)in_sizes; (void)n_in; (void)out_size; (void)ws_size;
  const float* feats[2][4] = {
      {(const float*)d_in[0], (const float*)d_in[1], (const float*)d_in[2], (const float*)d_in[3]},
      {(const float*)d_in[4], (const float*)d_in[5], (const float*)d_in[6], (const float*)d_in[7]}};
  const float* qe   = (const float*)d_in[8];
  const float* ng   = (const float*)d_in[9];
  const float* nb   = (const float*)d_in[10];
  const float* wq   = (const float*)d_in[11];
  const float* wk   = (const float*)d_in[12];
  const float* wv   = (const float*)d_in[13];
  const float* wp   = (const float*)d_in[14];
  const float* bp   = (const float*)d_in[15];
  const float* swqkv= (const float*)d_in[16];
  const float* swp  = (const float*)d_in[17];
  const float* sbp  = (const float*)d_in[18];

  float* ws = (float*)d_ws;
  float* KVp   = ws + O_KV;
  float* QBUFp = ws + O_QBUF;
  float* QKVp  = ws + O_QKV;
  float* QSAp  = ws + O_QSA;
  float* QHATp = ws + O_QHAT;
  float* QNp   = ws + O_QN;
  float* SAOp  = ws + O_SAO;
  float* OCAp  = ws + O_OCA;
  float* Q12p  = ws + O_Q12;
  unsigned short* WTHp = (unsigned short*)(ws + O_WTH);
  unsigned short* WTLp = (unsigned short*)(ws + O_WTL);
  float* WQp   = ws + O_WQ;
  float* BKVp  = ws + O_BKV;
  float* BQp   = ws + O_BQ;
  float* POp   = ws + O_PO;
  float* PMp   = ws + O_PM;
  float* PLp   = ws + O_PL;
  float* MSp   = ws + O_MS;
  float* RSTp  = ws + O_RST;
  float* STATSp= ws + O_STATS;

  const int HWs[4] = {4096, 1024, 256, 64};
  const int VOs[4] = {0, 16384, 20480, 21504};

  fold_w2_kernel<<<4608, 256, 0, stream>>>(ng, wk, wv, wq, WTHp, WTLp, WQp);
  fold_b_kernel<<<18, 256, 0, stream>>>(nb, wk, wv, wq, BKVp, BQp);
  for (int v = 0; v < 2; ++v)
    for (int l = 0; l < 4; ++l)
      ln_stats_kernel<<<dim3(HWs[l] / 64, 4), 256, 0, stream>>>(
          feats[v][l], STATSp, v * 21760 + VOs[l], HWs[l]);
  init_q_kernel<<<1600, 256, 0, stream>>>(qe, QBUFp);

  const int4 saStart = make_int4(0, 32, 64, 96);
  const int4 saNch   = make_int4(1, 1, 1, 1);
  const int4 saNk    = make_int4(100, 100, 100, 100);
  const int4 saKoff  = make_int4(0, 400, 800, 1200);
  const int4 saKstrb = make_int4(100, 100, 100, 100);
  const int4 caStart = make_int4(0, 1024, 1280, 1344);  // 128-key chunks
  const int4 caNch   = make_int4(32, 8, 2, 1);
  const int4 caNk    = make_int4(4096, 1024, 256, 64);
  const int4 caKoff  = make_int4(0, 16384, 20480, 21504);
  const int4 caKstrb = make_int4(4096, 1024, 256, 64);

  for (int d = 0; d < 6; ++d) {
    // --- self attention ---
    gemm256_kernel<<<dim3(12, 25), 256, 0, stream>>>(QBUFp, swqkv + (long)d * 196608, nullptr,
                                                     QKVp, 1600, 768);
    flash_kernel<<<128, 256, 0, stream>>>(QKVp, 768, QKVp + 256, QKVp + 512, 768,
                                          saStart, saNch, saNk, saKoff, saKstrb, POp, PMp, PLp);
    combine_kernel<<<128, 256, 0, stream>>>(POp, PMp, PLp, saStart, saNch, SAOp, 256);
    gemm256_kernel<<<dim3(4, 25), 256, 0, stream>>>(SAOp, swp + (long)d * 65536, sbp + d * 256,
                                                    QSAp, 1600, 256);
    // --- cross-attention query projection ---
    row_ln_kernel<<<1600, 256, 0, stream>>>(QSAp, QHATp);
    gemm256_kernel<<<dim3(4, 25), 256, 0, stream>>>(QHATp, WQp + (long)d * 65536, BQp + d * 256,
                                                    QNp, 1600, 256);
    // --- cross attention per view ---
    for (int v = 0; v < 2; ++v) {
      gemm_kv_mfma_kernel<<<dim3(8, 340), 256, 0, stream>>>(
          feats[v][0], feats[v][1], feats[v][2], feats[v][3], STATSp, v * 21760,
          WTHp + (long)d * 131072, WTLp + (long)d * 131072, BKVp + d * 512, KVp);
      flash_kernel<<<1376, 256, 0, stream>>>(QNp, 256, KVp, KVp + 256, 512,
                                             caStart, caNch, caNk, caKoff, caKstrb,
                                             POp, PMp, PLp);
      combine_kernel<<<128, 256, 0, stream>>>(POp, PMp, PLp, caStart, caNch,
                                              OCAp + (long)v * 409600, 256);
    }
    gemm256_kernel<<<dim3(4, 50), 256, 0, stream>>>(OCAp, wp + (long)d * 65536, bp + d * 256,
                                                    Q12p, 3200, 256);
    // --- matching fusion + channel softmax ---
    fuse_ms_kernel<<<dim3(16, 16), 256, 0, stream>>>(Q12p, Q12p + 409600, MSp);
    fuse_stats_kernel<<<16, 256, 0, stream>>>(MSp, RSTp);
    fuse_apply_kernel<<<dim3(16, 10), 256, 0, stream>>>(MSp, RSTp, Q12p, Q12p + 409600,
                                                        QSAp, QBUFp);
  }
  hipMemcpyAsync(d_out, QBUFp, 409600 * sizeof(float), hipMemcpyDeviceToDevice, stream);
}

// Round 3
// 2770.492 us; speedup vs baseline: 1.6139x; 1.6139x over previous
//
#include <hip/hip_runtime.h>

// ---------------------------------------------------------------------------
// VolumeAttention: 4 feature levels x 6 decoder depths, B=4, NQ=100, C=256, H=8
// Round 3: combine_kernel flattened over (lbh, qi, hd) -> grid (128,13)x256
//   (was 128 blocks, 1.8% occupancy, 163 us/dispatch = 2 ms total).
// Everything else unchanged from round 2.
// ---------------------------------------------------------------------------

#define DI __device__ __forceinline__

typedef __attribute__((ext_vector_type(8))) short bf16x8;
typedef __attribute__((ext_vector_type(4))) float f32x4;

// ws offsets in floats
constexpr long O_KV    = 0;                        // [21760][512] per-view K|V
constexpr long O_QBUF  = O_KV    + 21760L * 512;   // [1600][256] current q
constexpr long O_QKV   = O_QBUF  + 409600;         // [1600][768] self-attn qkv
constexpr long O_QSA   = O_QKV   + 1228800;        // [1600][256]
constexpr long O_QHAT  = O_QSA   + 409600;         // [1600][256]
constexpr long O_QN    = O_QHAT  + 409600;         // [1600][256]
constexpr long O_SAO   = O_QN    + 409600;         // [1600][256]
constexpr long O_OCA   = O_SAO   + 409600;         // [2][1600][256]
constexpr long O_Q12   = O_OCA   + 819200;         // [2][1600][256]
constexpr long O_WTH   = O_Q12   + 819200;         // [6][512][256] ushort hi
constexpr long O_WTL   = O_WTH   + 393216;         // [6][512][256] ushort lo
constexpr long O_WQ    = O_WTL   + 393216;         // [6][256][256] folded Wq fp32
constexpr long O_BKV   = O_WQ    + 393216;         // [6][512]
constexpr long O_BQ    = O_BKV   + 3072;           // [6][256]
constexpr long O_PO    = O_BQ    + 1536;           // [1376][3200] flash partial O
constexpr long O_PM    = O_PO    + 1376L * 3200;   // [1376][128]
constexpr long O_PL    = O_PM    + 176128;         // [1376][128]
constexpr long O_MS    = O_PL    + 176128;         // [16][128][128]
constexpr long O_RST   = O_MS    + 262144;         // [4][16][128]
constexpr long O_STATS = O_RST   + 8192;           // [43520][2] token mean/rstd
constexpr long WS_FLOATS = O_STATS + 87040;        // ~89.4 MB

DI int sel4(int4 v, int i) { return i == 0 ? v.x : (i == 1 ? v.y : (i == 2 ? v.z : v.w)); }
DI float dot4(float4 a, float4 b) {
  float s = a.x * b.x;
  s = fmaf(a.y, b.y, s); s = fmaf(a.z, b.z, s); s = fmaf(a.w, b.w, s);
  return s;
}
DI unsigned short bf_rne(float x) {
  unsigned u = __float_as_uint(x);
  u += 0x7fffu + ((u >> 16) & 1u);
  return (unsigned short)(u >> 16);
}
DI float bf2f(unsigned short h) { return __uint_as_float(((unsigned)h) << 16); }

// --- fold LN affine into projections; KV weights -> transposed split-bf16 --
__global__ void fold_w2_kernel(const float* __restrict__ ng, const float* __restrict__ wk,
                               const float* __restrict__ wv, const float* __restrict__ wq,
                               unsigned short* __restrict__ WTh, unsigned short* __restrict__ WTl,
                               float* __restrict__ wqo) {
  long idx = (long)blockIdx.x * 256 + threadIdx.x;
  const long T1 = 6L * 512 * 256;
  if (idx < T1) {
    int d = idx / (512 * 256); int r = idx % (512 * 256); int n = r / 256; int k = r % 256;
    float g = ng[d * 256 + k];
    float w = (n < 256) ? wk[((long)(d * 256 + k)) * 256 + n]
                        : wv[((long)(d * 256 + k)) * 256 + (n - 256)];
    w *= g;
    unsigned short h = bf_rne(w);
    WTh[idx] = h;
    WTl[idx] = bf_rne(w - bf2f(h));
  } else {
    long j = idx - T1;
    if (j < 6L * 256 * 256) {
      int d = j / 65536; int r = j % 65536; int c = r / 256; int n = r % 256;
      wqo[j] = ng[d * 256 + c] * wq[((long)(d * 256 + c)) * 256 + n];
    }
  }
}

__global__ void fold_b_kernel(const float* __restrict__ nb, const float* __restrict__ wk,
                              const float* __restrict__ wv, const float* __restrict__ wq,
                              float* __restrict__ bkvo, float* __restrict__ bqo) {
  int idx = blockIdx.x * 256 + threadIdx.x;
  if (idx >= 6 * 768) return;
  int d = idx / 768, j = idx % 768;
  float s = 0.f;
  if (j < 256) {
    for (int c = 0; c < 256; ++c) s = fmaf(nb[d * 256 + c], wk[(d * 256 + c) * 256 + j], s);
    bkvo[d * 512 + j] = s;
  } else if (j < 512) {
    int n = j - 256;
    for (int c = 0; c < 256; ++c) s = fmaf(nb[d * 256 + c], wv[(d * 256 + c) * 256 + n], s);
    bkvo[d * 512 + j] = s;
  } else {
    int n = j - 512;
    for (int c = 0; c < 256; ++c) s = fmaf(nb[d * 256 + c], wq[(d * 256 + c) * 256 + n], s);
    bqo[d * 256 + n] = s;
  }
}

// --- per-token LN statistics of feature maps ------------------------------
__global__ __launch_bounds__(256) void ln_stats_kernel(const float* __restrict__ feat,
                                                       float* __restrict__ stats,
                                                       int rowBase, int HW) {
  __shared__ float sred[4][64];
  __shared__ float qred[4][64];
  int b = blockIdx.y, t0 = blockIdx.x * 64;
  int tx = threadIdx.x & 63, ty = threadIdx.x >> 6;
  const float* fb = feat + (long)b * 256 * HW;
  float s = 0.f, q = 0.f;
  for (int k = 0; k < 64; ++k) {
    int c = ty * 64 + k;
    float v = fb[(long)c * HW + t0 + tx];
    s += v; q += v * v;
  }
  sred[ty][tx] = s; qred[ty][tx] = q;
  __syncthreads();
  if (ty == 0) {
    float ts = sred[0][tx] + sred[1][tx] + sred[2][tx] + sred[3][tx];
    float tq = qred[0][tx] + qred[1][tx] + qred[2][tx] + qred[3][tx];
    float m = ts * (1.f / 256.f);
    float var = tq * (1.f / 256.f) - m * m;
    int row = rowBase + b * HW + t0 + tx;
    stats[row * 2 + 0] = m;
    stats[row * 2 + 1] = rsqrtf(var + 1e-5f);
  }
}

__global__ void init_q_kernel(const float* __restrict__ qe, float* __restrict__ qb) {
  int idx = blockIdx.x * 256 + threadIdx.x;
  if (idx < 1600 * 256) {
    int row = idx >> 8, c = idx & 255;
    qb[idx] = qe[(row % 100) * 256 + c];
  }
}

// --- generic fp32 GEMM: C[M,N] = A[M,256] @ W[256,N] (+bias) --------------
__global__ __launch_bounds__(256) void gemm256_kernel(const float* __restrict__ A,
                                                      const float* __restrict__ W,
                                                      const float* __restrict__ bias,
                                                      float* __restrict__ Co, int M, int N) {
  __shared__ float As[32][68];
  __shared__ float Ws[32][68];
  int tid = threadIdx.x;
  int tm = tid & 15, tn = tid >> 4;
  int m0 = blockIdx.y * 64, n0 = blockIdx.x * 64;
  float acc[4][4] = {};
  for (int kt = 0; kt < 8; ++kt) {
    __syncthreads();
#pragma unroll
    for (int it = 0; it < 2; ++it) {
      int i = tid + it * 256;
      int r = i >> 3, c4 = (i & 7) * 4;
      float4 f = *(const float4*)&A[(long)(m0 + r) * 256 + kt * 32 + c4];
      As[c4 + 0][r] = f.x; As[c4 + 1][r] = f.y; As[c4 + 2][r] = f.z; As[c4 + 3][r] = f.w;
    }
#pragma unroll
    for (int it = 0; it < 2; ++it) {
      int i = tid + it * 256;
      int r = i >> 4, c4 = (i & 15) * 4;
      *(float4*)&Ws[r][c4] = *(const float4*)&W[(long)(kt * 32 + r) * N + n0 + c4];
    }
    __syncthreads();
#pragma unroll
    for (int k = 0; k < 32; ++k) {
      float4 a4 = *(const float4*)&As[k][4 * tm];
      float4 b4 = *(const float4*)&Ws[k][4 * tn];
      float av[4] = {a4.x, a4.y, a4.z, a4.w};
      float bv[4] = {b4.x, b4.y, b4.z, b4.w};
#pragma unroll
      for (int i = 0; i < 4; ++i)
#pragma unroll
        for (int j = 0; j < 4; ++j) acc[i][j] = fmaf(av[i], bv[j], acc[i][j]);
    }
  }
  float bv4[4] = {0.f, 0.f, 0.f, 0.f};
  if (bias) {
#pragma unroll
    for (int j = 0; j < 4; ++j) bv4[j] = bias[n0 + 4 * tn + j];
  }
#pragma unroll
  for (int i = 0; i < 4; ++i) {
    int row = m0 + 4 * tm + i;
    float4 o;
    o.x = acc[i][0] + bv4[0]; o.y = acc[i][1] + bv4[1];
    o.z = acc[i][2] + bv4[2]; o.w = acc[i][3] + bv4[3];
    *(float4*)&Co[(long)row * N + n0 + 4 * tn] = o;
  }
}

// --- KV projection via MFMA, split-bf16 ------------------------------------
__global__ __launch_bounds__(256) void gemm_kv_mfma_kernel(
    const float* __restrict__ f0, const float* __restrict__ f1,
    const float* __restrict__ f2, const float* __restrict__ f3,
    const float* __restrict__ stats, int vbase,
    const unsigned short* __restrict__ Wh, const unsigned short* __restrict__ Wl,
    const float* __restrict__ bias, float* __restrict__ Co) {
  __shared__ unsigned short Ah[64][72], Al[64][72];   // [m][k] bf16, pad 8
  __shared__ unsigned short Bh[64][72], Bl[64][72];   // [n][k] bf16
  __shared__ float sm[64], sr[64];
  int tid = threadIdx.x;
  int m0 = blockIdx.y * 64, n0 = blockIdx.x * 64;
  const float* fp; int HW, rel;
  if (m0 < 16384)      { fp = f0; HW = 4096; rel = m0; }
  else if (m0 < 20480) { fp = f1; HW = 1024; rel = m0 - 16384; }
  else if (m0 < 21504) { fp = f2; HW = 256;  rel = m0 - 20480; }
  else                 { fp = f3; HW = 64;   rel = m0 - 21504; }
  int b = rel / HW, t0 = rel % HW;
  const float* fb = fp + (long)b * 256 * HW + t0;
  if (tid < 64) {
    sm[tid] = stats[(vbase + m0 + tid) * 2 + 0];
    sr[tid] = stats[(vbase + m0 + tid) * 2 + 1];
  }
  int wv = tid >> 6, lane = tid & 63;
  int fr = lane & 15;   // MFMA row/col within 16
  int kq = lane >> 4;   // k-quarter: k0 = 8*kq
  f32x4 acc[4];
#pragma unroll
  for (int c = 0; c < 4; ++c)
#pragma unroll
    for (int r = 0; r < 4; ++r) acc[c][r] = 0.f;
  __syncthreads();  // sm/sr ready
  for (int kc = 0; kc < 4; ++kc) {  // 4 chunks of 64 k
    {
      float mean = sm[lane], rstd = sr[lane];
#pragma unroll
      for (int pass = 0; pass < 4; ++pass) {
        int k = pass * 16 + wv * 4;
        float xs[4];
#pragma unroll
        for (int i = 0; i < 4; ++i)
          xs[i] = (fb[(long)(kc * 64 + k + i) * HW + lane] - mean) * rstd;
        ushort4 uh, ul;
        uh.x = bf_rne(xs[0]); ul.x = bf_rne(xs[0] - bf2f(uh.x));
        uh.y = bf_rne(xs[1]); ul.y = bf_rne(xs[1] - bf2f(uh.y));
        uh.z = bf_rne(xs[2]); ul.z = bf_rne(xs[2] - bf2f(uh.z));
        uh.w = bf_rne(xs[3]); ul.w = bf_rne(xs[3] - bf2f(uh.w));
        *(ushort4*)&Ah[lane][k] = uh;
        *(ushort4*)&Al[lane][k] = ul;
      }
    }
    {
      int ks = (tid & 15) * 4;
#pragma unroll
      for (int pass = 0; pass < 4; ++pass) {
        int n = pass * 16 + (tid >> 4);
        long g = (long)(n0 + n) * 256 + kc * 64 + ks;
        *(ushort4*)&Bh[n][ks] = *(const ushort4*)&Wh[g];
        *(ushort4*)&Bl[n][ks] = *(const ushort4*)&Wl[g];
      }
    }
    __syncthreads();
#pragma unroll
    for (int s = 0; s < 2; ++s) {  // two K=32 steps
      int k0 = s * 32 + kq * 8;
      bf16x8 a_h = *(const bf16x8*)&Ah[wv * 16 + fr][k0];
      bf16x8 a_l = *(const bf16x8*)&Al[wv * 16 + fr][k0];
#pragma unroll
      for (int c = 0; c < 4; ++c) {
        bf16x8 b_h = *(const bf16x8*)&Bh[c * 16 + fr][k0];
        bf16x8 b_l = *(const bf16x8*)&Bl[c * 16 + fr][k0];
        acc[c] = __builtin_amdgcn_mfma_f32_16x16x32_bf16(a_h, b_h, acc[c], 0, 0, 0);
        acc[c] = __builtin_amdgcn_mfma_f32_16x16x32_bf16(a_l, b_h, acc[c], 0, 0, 0);
        acc[c] = __builtin_amdgcn_mfma_f32_16x16x32_bf16(a_h, b_l, acc[c], 0, 0, 0);
      }
    }
    __syncthreads();
  }
  int row0 = m0 + wv * 16 + kq * 4;
#pragma unroll
  for (int c = 0; c < 4; ++c) {
    float bv = bias[n0 + c * 16 + fr];
#pragma unroll
    for (int r = 0; r < 4; ++r)
      Co[(long)(row0 + r) * 512 + n0 + c * 16 + fr] = acc[c][r] + bv;
  }
}

// --- row LayerNorm (no affine) ---------------------------------------------
__global__ __launch_bounds__(256) void row_ln_kernel(const float* __restrict__ in,
                                                     float* __restrict__ out) {
  __shared__ float s1[4], s2[4];
  long r = blockIdx.x;
  float x = in[r * 256 + threadIdx.x];
  float vs = x, vq = x * x;
  for (int o = 32; o; o >>= 1) { vs += __shfl_xor(vs, o); vq += __shfl_xor(vq, o); }
  int w = threadIdx.x >> 6;
  if ((threadIdx.x & 63) == 0) { s1[w] = vs; s2[w] = vq; }
  __syncthreads();
  float ts = s1[0] + s1[1] + s1[2] + s1[3];
  float tq = s2[0] + s2[1] + s2[2] + s2[3];
  float m = ts * (1.f / 256.f);
  float var = tq * (1.f / 256.f) - m * m;
  out[r * 256 + threadIdx.x] = (x - m) * rsqrtf(var + 1e-5f);
}

// --- flash split-K attention (128-key chunks) ------------------------------
__global__ __launch_bounds__(256) void flash_kernel(const float* __restrict__ qp, int qld,
                                                    const float* __restrict__ kb,
                                                    const float* __restrict__ vb, int kvld,
                                                    int4 startv, int4 nchv, int4 nkv,
                                                    int4 koffv, int4 kstrbv,
                                                    float* __restrict__ po,
                                                    float* __restrict__ pm,
                                                    float* __restrict__ pl) {
  __shared__ float Kt[32][36];
  __shared__ float Vt[32][36];
  int bid = blockIdx.x;
  int s1 = startv.y, s2 = startv.z, s3 = startv.w;
  int l = (bid < s1) ? 0 : (bid < s2) ? 1 : (bid < s3) ? 2 : 3;
  int r = bid - sel4(startv, l);
  int nc = sel4(nchv, l);
  int b = r / (8 * nc);
  int h = (r / nc) & 7;
  int ch = r % nc;
  int Nk = sel4(nkv, l);
  int qr0 = (l * 4 + b) * 100;
  int kr0 = sel4(koffv, l) + b * sel4(kstrbv, l);
  int j0 = ch * 128;
  int jn = min(128, Nk - j0);
  int tiles = (jn + 31) >> 5;
  int tid = threadIdx.x;
  int qi = tid >> 1, half = tid & 1, ho = half * 16, jb = half * 16;
  const float SC = 0.17677669529663689f;  // 32^-0.5
  float4 q8[8];
  if (qi < 100) {
    const float* qrow = qp + (long)(qr0 + qi) * qld + h * 32;
#pragma unroll
    for (int k = 0; k < 8; ++k) {
      float4 f = *(const float4*)&qrow[4 * k];
      q8[k] = make_float4(f.x * SC, f.y * SC, f.z * SC, f.w * SC);
    }
  } else {
#pragma unroll
    for (int k = 0; k < 8; ++k) q8[k] = make_float4(0.f, 0.f, 0.f, 0.f);
  }
  float m = -1e30f, lsum = 0.f;
  float o[16];
#pragma unroll
  for (int i = 0; i < 16; ++i) o[i] = 0.f;

  for (int kt = 0; kt < tiles; ++kt) {
    __syncthreads();
    {
      int rr = tid >> 3, c4 = (tid & 7) * 4;
      int jr = kt * 32 + rr;
      float4 kf = make_float4(0.f, 0.f, 0.f, 0.f), vf = kf;
      if (jr < jn) {
        long g = (long)(kr0 + j0 + jr) * kvld + h * 32 + c4;
        kf = *(const float4*)&kb[g];
        vf = *(const float4*)&vb[g];
      }
      *(float4*)&Kt[rr][c4 ^ (rr & 16)] = kf;   // bank swizzle on K only
      *(float4*)&Vt[rr][c4] = vf;
    }
    __syncthreads();
    float sv[16];
#pragma unroll
    for (int j = 0; j < 16; ++j) {
      float s = 0.f;
#pragma unroll
      for (int k4 = 0; k4 < 8; ++k4) {
        float4 kv = *(const float4*)&Kt[jb + j][(4 * k4) ^ jb];
        s = fmaf(q8[k4].x, kv.x, s); s = fmaf(q8[k4].y, kv.y, s);
        s = fmaf(q8[k4].z, kv.z, s); s = fmaf(q8[k4].w, kv.w, s);
      }
      int jglob = j0 + kt * 32 + jb + j;
      sv[j] = (jglob < Nk) ? s : -1e30f;
    }
    float tmax = sv[0];
#pragma unroll
    for (int j = 1; j < 16; ++j) tmax = fmaxf(tmax, sv[j]);
    tmax = fmaxf(tmax, __shfl_xor(tmax, 1));
    float mnew = fmaxf(m, tmax);
    float scale = __expf(m - mnew);
    float p[16]; float psum = 0.f;
#pragma unroll
    for (int j = 0; j < 16; ++j) {
      int jglob = j0 + kt * 32 + jb + j;
      float e = (jglob < Nk) ? __expf(sv[j] - mnew) : 0.f;
      p[j] = e; psum += e;
    }
    psum += __shfl_xor(psum, 1);
    lsum = lsum * scale + psum;
    m = mnew;
#pragma unroll
    for (int i = 0; i < 16; ++i) o[i] *= scale;
    float pO[16];
#pragma unroll
    for (int j = 0; j < 16; ++j) pO[j] = __shfl_xor(p[j], 1);
    int jbO = jb ^ 16;
#pragma unroll
    for (int j = 0; j < 16; ++j) {
      float pj = p[j];
      const float* vrow = &Vt[jb + j][ho];
#pragma unroll
      for (int k = 0; k < 4; ++k) {
        float4 v4 = *(const float4*)&vrow[4 * k];
        o[4 * k + 0] = fmaf(pj, v4.x, o[4 * k + 0]);
        o[4 * k + 1] = fmaf(pj, v4.y, o[4 * k + 1]);
        o[4 * k + 2] = fmaf(pj, v4.z, o[4 * k + 2]);
        o[4 * k + 3] = fmaf(pj, v4.w, o[4 * k + 3]);
      }
    }
#pragma unroll
    for (int j = 0; j < 16; ++j) {
      float pj = pO[j];
      const float* vrow = &Vt[jbO + j][ho];
#pragma unroll
      for (int k = 0; k < 4; ++k) {
        float4 v4 = *(const float4*)&vrow[4 * k];
        o[4 * k + 0] = fmaf(pj, v4.x, o[4 * k + 0]);
        o[4 * k + 1] = fmaf(pj, v4.y, o[4 * k + 1]);
        o[4 * k + 2] = fmaf(pj, v4.z, o[4 * k + 2]);
        o[4 * k + 3] = fmaf(pj, v4.w, o[4 * k + 3]);
      }
    }
  }
  if (qi < 100) {
    float* pod = po + (long)bid * 3200 + qi * 32 + ho;
#pragma unroll
    for (int k = 0; k < 4; ++k)
      *(float4*)&pod[4 * k] = make_float4(o[4 * k], o[4 * k + 1], o[4 * k + 2], o[4 * k + 3]);
    if (half == 0) { pm[bid * 128 + qi] = m; pl[bid * 128 + qi] = lsum; }
  }
}

// --- combine flash partials (flattened: one thread per output element) ------
// grid (128 lbh, 13 chunks-of-256 over 3200 elements)
__global__ __launch_bounds__(256) void combine_kernel(const float* __restrict__ po,
                                                      const float* __restrict__ pm,
                                                      const float* __restrict__ pl,
                                                      int4 startv, int4 nchv,
                                                      float* __restrict__ outp, int outld) {
  int bid = blockIdx.x;
  int l = bid >> 5, rr = bid & 31, b = rr >> 3, h = rr & 7;
  int nc = sel4(nchv, l);
  int sb = sel4(startv, l) + (b * 8 + h) * nc;
  int qr0 = (l * 4 + b) * 100;
  int idx = blockIdx.y * 256 + threadIdx.x;
  if (idx >= 3200) return;
  int qi = idx >> 5, hd = idx & 31;
  float mstar = -1e30f;
  for (int c = 0; c < nc; ++c) mstar = fmaxf(mstar, pm[(sb + c) * 128 + qi]);
  float Lt = 0.f, val = 0.f;
  for (int c = 0; c < nc; ++c) {
    float w = __expf(pm[(sb + c) * 128 + qi] - mstar);
    Lt = fmaf(w, pl[(sb + c) * 128 + qi], Lt);
    val = fmaf(w, po[(long)(sb + c) * 3200 + qi * 32 + hd], val);
  }
  outp[(long)(qr0 + qi) * outld + h * 32 + hd] = val / Lt;
}

// --- ms = q1 @ q2^T ---------------------------------------------------------
__global__ __launch_bounds__(256) void fuse_ms_kernel(const float* __restrict__ q1,
                                                      const float* __restrict__ q2,
                                                      float* __restrict__ ms) {
  __shared__ float a[32][132];
  __shared__ float bsh[32][132];
  int lb = blockIdx.x;
  int it = blockIdx.y >> 2, jt = blockIdx.y & 3;
  int tid = threadIdx.x;
  int ti = tid & 15, tj = tid >> 4;
  float acc[2][2] = {};
  for (int chalf = 0; chalf < 2; ++chalf) {
    __syncthreads();
#pragma unroll
    for (int k = 0; k < 4; ++k) {
      int i = tid + k * 256;
      int rr = i >> 5, c4 = (i & 31) * 4;
      int row1 = it * 32 + rr, row2 = jt * 32 + rr;
      float4 fa = make_float4(0.f, 0.f, 0.f, 0.f), fb = fa;
      if (row1 < 100) fa = *(const float4*)&q1[(long)(lb * 100 + row1) * 256 + chalf * 128 + c4];
      if (row2 < 100) fb = *(const float4*)&q2[(long)(lb * 100 + row2) * 256 + chalf * 128 + c4];
      *(float4*)&a[rr][c4] = fa;
      *(float4*)&bsh[rr][c4] = fb;
    }
    __syncthreads();
#pragma unroll
    for (int k4 = 0; k4 < 32; ++k4) {
      float4 a0 = *(const float4*)&a[2 * ti][4 * k4];
      float4 a1 = *(const float4*)&a[2 * ti + 1][4 * k4];
      float4 b0 = *(const float4*)&bsh[2 * tj][4 * k4];
      float4 b1 = *(const float4*)&bsh[2 * tj + 1][4 * k4];
      acc[0][0] += dot4(a0, b0); acc[0][1] += dot4(a0, b1);
      acc[1][0] += dot4(a1, b0); acc[1][1] += dot4(a1, b1);
    }
  }
#pragma unroll
  for (int i = 0; i < 2; ++i)
#pragma unroll
    for (int j = 0; j < 2; ++j)
      ms[(long)(lb * 128 + it * 32 + 2 * ti + i) * 128 + jt * 32 + 2 * tj + j] = acc[i][j];
}

// --- row & column softmax stats of ms --------------------------------------
__global__ void fuse_stats_kernel(const float* __restrict__ ms, float* __restrict__ rst) {
  int lb = blockIdx.x, tid = threadIdx.x;
  if (tid < 100) {
    const float* row = ms + (long)(lb * 128 + tid) * 128;
    float mx = row[0];
    for (int j = 1; j < 100; ++j) mx = fmaxf(mx, row[j]);
    float s = 0.f;
    for (int j = 0; j < 100; ++j) s += __expf(row[j] - mx);
    rst[(0 * 16 + lb) * 128 + tid] = mx;
    rst[(1 * 16 + lb) * 128 + tid] = s;
  } else if (tid >= 128 && tid < 228) {
    int j = tid - 128;
    const float* colp = ms + (long)lb * 128 * 128 + j;
    float mx = colp[0];
    for (int i = 1; i < 100; ++i) mx = fmaxf(mx, colp[i * 128]);
    float s = 0.f;
    for (int i = 0; i < 100; ++i) s += __expf(colp[i * 128] - mx);
    rst[(2 * 16 + lb) * 128 + j] = mx;
    rst[(3 * 16 + lb) * 128 + j] = s;
  }
}

// --- r1/r2 mixing + final channel softmax -----------------------------------
__global__ __launch_bounds__(256) void fuse_apply_kernel(const float* __restrict__ ms,
                                                         const float* __restrict__ rst,
                                                         const float* __restrict__ q1,
                                                         const float* __restrict__ q2,
                                                         const float* __restrict__ qsa,
                                                         float* __restrict__ qout) {
  __shared__ float pr[100], pc[100];
  __shared__ float red1[4], red2[4];
  int lb = blockIdx.x, qc = blockIdx.y, tid = threadIdx.x;
  for (int ii = 0; ii < 10; ++ii) {
    int i = qc * 10 + ii;
    long r = lb * 100 + i;
    if (tid < 100) {
      float rm = rst[(0 * 16 + lb) * 128 + i], rs = rst[(1 * 16 + lb) * 128 + i];
      pr[tid] = __expf(ms[(long)(lb * 128 + i) * 128 + tid] - rm) / rs;
    } else if (tid >= 128 && tid < 228) {
      int i2 = tid - 128;
      float cm = rst[(2 * 16 + lb) * 128 + i], cs = rst[(3 * 16 + lb) * 128 + i];
      pc[i2] = __expf(ms[(long)(lb * 128 + i2) * 128 + i] - cm) / cs;
    }
    __syncthreads();
    float acc1 = 0.f, acc2 = 0.f;
    for (int j = 0; j < 100; ++j) acc1 = fmaf(pr[j], q2[(long)(lb * 100 + j) * 256 + tid], acc1);
    for (int j = 0; j < 100; ++j) acc2 = fmaf(pc[j], q1[(long)(lb * 100 + j) * 256 + tid], acc2);
    float z = qsa[r * 256 + tid] + q1[r * 256 + tid] + acc1 + q2[r * 256 + tid] + acc2;
    float v = z;
    for (int off = 32; off; off >>= 1) v = fmaxf(v, __shfl_xor(v, off));
    int w = tid >> 6;
    if ((tid & 63) == 0) red1[w] = v;
    __syncthreads();
    float zm = fmaxf(fmaxf(red1[0], red1[1]), fmaxf(red1[2], red1[3]));
    float e = __expf(z - zm);
    float sv = e;
    for (int off = 32; off; off >>= 1) sv += __shfl_xor(sv, off);
    if ((tid & 63) == 0) red2[w] = sv;
    __syncthreads();
    float es = red2[0] + red2[1] + red2[2] + red2[3];
    qout[r * 256 + tid] = e / es;
    __syncthreads();
  }
}

// ---------------------------------------------------------------------------
extern "C" void kernel_launch(void* const* d_in, const int* in_sizes, int n_in,
                              void* d_out, int out_size, void* d_ws, size_t ws_size,
                              hipStream_t stream) {
  (void)in_sizes; (void)n_in; (void)out_size; (void)ws_size;
  const float* feats[2][4] = {
      {(const float*)d_in[0], (const float*)d_in[1], (const float*)d_in[2], (const float*)d_in[3]},
      {(const float*)d_in[4], (const float*)d_in[5], (const float*)d_in[6], (const float*)d_in[7]}};
  const float* qe   = (const float*)d_in[8];
  const float* ng   = (const float*)d_in[9];
  const float* nb   = (const float*)d_in[10];
  const float* wq   = (const float*)d_in[11];
  const float* wk   = (const float*)d_in[12];
  const float* wv   = (const float*)d_in[13];
  const float* wp   = (const float*)d_in[14];
  const float* bp   = (const float*)d_in[15];
  const float* swqkv= (const float*)d_in[16];
  const float* swp  = (const float*)d_in[17];
  const float* sbp  = (const float*)d_in[18];

  float* ws = (float*)d_ws;
  float* KVp   = ws + O_KV;
  float* QBUFp = ws + O_QBUF;
  float* QKVp  = ws + O_QKV;
  float* QSAp  = ws + O_QSA;
  float* QHATp = ws + O_QHAT;
  float* QNp   = ws + O_QN;
  float* SAOp  = ws + O_SAO;
  float* OCAp  = ws + O_OCA;
  float* Q12p  = ws + O_Q12;
  unsigned short* WTHp = (unsigned short*)(ws + O_WTH);
  unsigned short* WTLp = (unsigned short*)(ws + O_WTL);
  float* WQp   = ws + O_WQ;
  float* BKVp  = ws + O_BKV;
  float* BQp   = ws + O_BQ;
  float* POp   = ws + O_PO;
  float* PMp   = ws + O_PM;
  float* PLp   = ws + O_PL;
  float* MSp   = ws + O_MS;
  float* RSTp  = ws + O_RST;
  float* STATSp= ws + O_STATS;

  const int HWs[4] = {4096, 1024, 256, 64};
  const int VOs[4] = {0, 16384, 20480, 21504};

  fold_w2_kernel<<<4608, 256, 0, stream>>>(ng, wk, wv, wq, WTHp, WTLp, WQp);
  fold_b_kernel<<<18, 256, 0, stream>>>(nb, wk, wv, wq, BKVp, BQp);
  for (int v = 0; v < 2; ++v)
    for (int l = 0; l < 4; ++l)
      ln_stats_kernel<<<dim3(HWs[l] / 64, 4), 256, 0, stream>>>(
          feats[v][l], STATSp, v * 21760 + VOs[l], HWs[l]);
  init_q_kernel<<<1600, 256, 0, stream>>>(qe, QBUFp);

  const int4 saStart = make_int4(0, 32, 64, 96);
  const int4 saNch   = make_int4(1, 1, 1, 1);
  const int4 saNk    = make_int4(100, 100, 100, 100);
  const int4 saKoff  = make_int4(0, 400, 800, 1200);
  const int4 saKstrb = make_int4(100, 100, 100, 100);
  const int4 caStart = make_int4(0, 1024, 1280, 1344);  // 128-key chunks
  const int4 caNch   = make_int4(32, 8, 2, 1);
  const int4 caNk    = make_int4(4096, 1024, 256, 64);
  const int4 caKoff  = make_int4(0, 16384, 20480, 21504);
  const int4 caKstrb = make_int4(4096, 1024, 256, 64);

  for (int d = 0; d < 6; ++d) {
    // --- self attention ---
    gemm256_kernel<<<dim3(12, 25), 256, 0, stream>>>(QBUFp, swqkv + (long)d * 196608, nullptr,
                                                     QKVp, 1600, 768);
    flash_kernel<<<128, 256, 0, stream>>>(QKVp, 768, QKVp + 256, QKVp + 512, 768,
                                          saStart, saNch, saNk, saKoff, saKstrb, POp, PMp, PLp);
    combine_kernel<<<dim3(128, 13), 256, 0, stream>>>(POp, PMp, PLp, saStart, saNch, SAOp, 256);
    gemm256_kernel<<<dim3(4, 25), 256, 0, stream>>>(SAOp, swp + (long)d * 65536, sbp + d * 256,
                                                    QSAp, 1600, 256);
    // --- cross-attention query projection ---
    row_ln_kernel<<<1600, 256, 0, stream>>>(QSAp, QHATp);
    gemm256_kernel<<<dim3(4, 25), 256, 0, stream>>>(QHATp, WQp + (long)d * 65536, BQp + d * 256,
                                                    QNp, 1600, 256);
    // --- cross attention per view ---
    for (int v = 0; v < 2; ++v) {
      gemm_kv_mfma_kernel<<<dim3(8, 340), 256, 0, stream>>>(
          feats[v][0], feats[v][1], feats[v][2], feats[v][3], STATSp, v * 21760,
          WTHp + (long)d * 131072, WTLp + (long)d * 131072, BKVp + d * 512, KVp);
      flash_kernel<<<1376, 256, 0, stream>>>(QNp, 256, KVp, KVp + 256, 512,
                                             caStart, caNch, caNk, caKoff, caKstrb,
                                             POp, PMp, PLp);
      combine_kernel<<<dim3(128, 13), 256, 0, stream>>>(POp, PMp, PLp, caStart, caNch,
                                                        OCAp + (long)v * 409600, 256);
    }
    gemm256_kernel<<<dim3(4, 50), 256, 0, stream>>>(OCAp, wp + (long)d * 65536, bp + d * 256,
                                                    Q12p, 3200, 256);
    // --- matching fusion + channel softmax ---
    fuse_ms_kernel<<<dim3(16, 16), 256, 0, stream>>>(Q12p, Q12p + 409600, MSp);
    fuse_stats_kernel<<<16, 256, 0, stream>>>(MSp, RSTp);
    fuse_apply_kernel<<<dim3(16, 10), 256, 0, stream>>>(MSp, RSTp, Q12p, Q12p + 409600,
                                                        QSAp, QBUFp);
  }
  hipMemcpyAsync(d_out, QBUFp, 409600 * sizeof(float), hipMemcpyDeviceToDevice, stream);
}